// Round 6
// baseline (425.423 us; speedup 1.0000x reference)
//
#include <hip/hip_runtime.h>
#include <math.h>

typedef _Float16 f16;
typedef _Float16 h4 __attribute__((ext_vector_type(4)));
typedef _Float16 h8 __attribute__((ext_vector_type(8)));
typedef float f32x4 __attribute__((ext_vector_type(4)));
typedef float f32x16 __attribute__((ext_vector_type(16)));
typedef unsigned int u32;
typedef u32 u32x2 __attribute__((ext_vector_type(2)));
typedef u32 u32x4 __attribute__((ext_vector_type(4)));

#define QSCALE 0.17677669529663689f  // 1/sqrt(32)

// ---------------- Kernel A: projection GEMM (f16 MFMA) ----------------
// grid (512 row-tiles, 2 phases). phase0: q_x -> {q(scaled), g(sigmoid)};
// phase1: kv_x -> {k, v(transposed store)}. Block 256 thr = 4 waves (2x2),
// out tile 128x128 per weight. LDS: X 32KB + W 32KB, XOR-swizzled 16B chunks.
__global__ __launch_bounds__(256) void proj_mfma(
    const float* __restrict__ q_x, const float* __restrict__ kv_x,
    const float* __restrict__ wq, const float* __restrict__ wk,
    const float* __restrict__ wv, const float* __restrict__ wg,
    const float* __restrict__ bg,
    f16* __restrict__ qb, f16* __restrict__ kb,
    f16* __restrict__ vbT, f16* __restrict__ gb)
{
    __shared__ char lds[65536];
    char* xl = lds;
    char* wl = lds + 32768;
    const int t = threadIdx.x;
    const int lane = t & 63, wave = t >> 6;
    const int wr = wave >> 1, wc = wave & 1;
    const int lo = lane & 15, hi = lane >> 4;
    const int phase = blockIdx.y;
    const int row0 = blockIdx.x * 128;
    const float* xsrc = phase ? kv_x : q_x;

    // stage X tile 128x128 fp32 -> f16 swizzled LDS
    #pragma unroll
    for (int j = 0; j < 16; ++j) {
        int f = t + 256 * j;
        int row = f >> 5, c4 = f & 31;
        float4 v = *(const float4*)(xsrc + (size_t)(row0 + row) * 128 + c4 * 4);
        h4 hv = {(f16)v.x, (f16)v.y, (f16)v.z, (f16)v.w};
        *(h4*)(xl + row * 256 + (((c4 >> 1) ^ (row & 7)) << 4) + ((c4 & 1) << 3)) = hv;
    }

    for (int sub = 0; sub < 2; ++sub) {
        const int pid = phase * 2 + sub;
        const float* w = (pid == 0) ? wq : (pid == 1) ? wg : (pid == 2) ? wk : wv;
        __syncthreads();  // xl ready (sub0) / wl reads done (sub1)
        #pragma unroll
        for (int j = 0; j < 16; ++j) {
            int f = t + 256 * j;
            int row = f >> 5, c4 = f & 31;
            float4 v = *(const float4*)(w + (size_t)row * 128 + c4 * 4);
            h4 hv = {(f16)v.x, (f16)v.y, (f16)v.z, (f16)v.w};
            *(h4*)(wl + row * 256 + (((c4 >> 1) ^ (row & 7)) << 4) + ((c4 & 1) << 3)) = hv;
        }
        __syncthreads();

        f32x4 acc[4][4];
        #pragma unroll
        for (int m = 0; m < 4; ++m)
            #pragma unroll
            for (int n = 0; n < 4; ++n) acc[m][n] = (f32x4){0.f, 0.f, 0.f, 0.f};

        #pragma unroll
        for (int kk = 0; kk < 4; ++kk) {
            const int swz = ((hi + 4 * kk) ^ (lo & 7)) << 4;
            h8 af[4], bf[4];
            #pragma unroll
            for (int m = 0; m < 4; ++m)
                af[m] = *(const h8*)(xl + (lo + 16 * m + 64 * wr) * 256 + swz);
            #pragma unroll
            for (int n = 0; n < 4; ++n)
                bf[n] = *(const h8*)(wl + (lo + 16 * n + 64 * wc) * 256 + swz);
            #pragma unroll
            for (int m = 0; m < 4; ++m)
                #pragma unroll
                for (int n = 0; n < 4; ++n)
                    acc[m][n] = __builtin_amdgcn_mfma_f32_16x16x32_f16(af[m], bf[n], acc[m][n], 0, 0, 0);
        }

        // epilogue: D[row=(l>>4)*4+r][col=l&15]
        #pragma unroll
        for (int n = 0; n < 4; ++n) {
            const int col = 64 * wc + 16 * n + lo;
            const float bgv = (pid == 1) ? bg[col] : 0.f;
            #pragma unroll
            for (int m = 0; m < 4; ++m) {
                if (pid == 3) {
                    // V transposed: vbT[((s*4+h)*32+dh)*256 + key]
                    int rg = row0 + 64 * wr + 16 * m + 4 * hi;
                    int sidx = rg >> 8, key = rg & 255;
                    int hh = col >> 5, dh = col & 31;
                    h4 hv = {(f16)acc[m][n][0], (f16)acc[m][n][1],
                             (f16)acc[m][n][2], (f16)acc[m][n][3]};
                    *(h4*)(vbT + (((size_t)sidx * 4 + hh) * 32 + dh) * 256 + key) = hv;
                } else {
                    f16* dst = (pid == 0) ? qb : (pid == 1) ? gb : kb;
                    #pragma unroll
                    for (int r = 0; r < 4; ++r) {
                        int rg = row0 + 64 * wr + 16 * m + 4 * hi + r;
                        float v = acc[m][n][r];
                        if (pid == 0) v *= QSCALE;
                        else if (pid == 1) v = 1.f / (1.f + __expf(-(v + bgv)));
                        dst[(size_t)rg * 128 + col] = (f16)v;
                    }
                }
            }
        }
    }
}

// ---------------- Kernel B: attention (swapped 32x32x16, chunked online softmax) ----------------
// grid (s=256, h=4); 4 waves; wave does 2 strips of 32 q (2 passes).
// K,V staged ONCE per block into LDS fragment-slot layout (linear 16B/lane reads).
// Keys processed in 2 chunks of 128 (acc[4] = 64 VGPR, no spill) with one
// online-softmax merge. QK^T as mfma(K,Q) -> D[key][q=lane&31]; bias1 C-init
// float4-vectorized; softmax in-lane + shfl_xor(32); PV B-frag from own regs.
__global__ __launch_bounds__(256, 4) void attn_mfma(
    const f16* __restrict__ qb, const f16* __restrict__ kb,
    const f16* __restrict__ vbT, const f16* __restrict__ gb,
    const float* __restrict__ bias1, const float* __restrict__ bias2,
    f16* __restrict__ ob)
{
    __shared__ char kvlds[32768];
    char* klds = kvlds;
    char* vlds = kvlds + 16384;
    const int s = blockIdx.x, h = blockIdx.y;
    const int t = threadIdx.x, wave = t >> 6, lane = t & 63;
    const int q32 = lane & 31;   // q column (QK, PV outputs); d row for V A-frag
    const int b = lane >> 5;     // lane half
    const size_t rowbase = (size_t)s * 256;
    const f16* kslab = kb + rowbase * 128 + h * 32;           // K[key][d], row 128
    const f16* vslab = vbT + ((size_t)s * 4 + h) * 32 * 256;  // V^T[d][key]
    const float* b1 = bias1 + (size_t)h * 65536;              // [q][k]
    const float* b2 = bias2 + (size_t)s * 256;                // [k]

    // ---- stage K: chunks (key, c): d-halves 8c..8c+7; slot = (key>>5)*4 + c ----
    #pragma unroll
    for (int it = 0; it < 4; ++it) {
        int idx = t + 256 * it;
        int key = idx >> 2, c = idx & 3;
        h8 v = *(const h8*)(kslab + (size_t)key * 128 + c * 8);
        *(h8*)(klds + ((key >> 5) * 4 + c) * 512 + (key & 31) * 16) = v;
    }
    // ---- stage V: chunks (d, kc): keys 8kc..8kc+7; slot = kc ----
    #pragma unroll
    for (int it = 0; it < 4; ++it) {
        int idx = t + 256 * it;
        int d = idx & 31, kc = idx >> 5;
        h8 v = *(const h8*)(vslab + (size_t)d * 256 + kc * 8);
        *(h8*)(vlds + kc * 512 + d * 16) = v;
    }
    __syncthreads();

    for (int pass = 0; pass < 2; ++pass) {
        const int q0 = pass * 128 + wave * 32;
        const float* b1row = b1 + (size_t)(q0 + q32) * 256;

        // Q B-frags: B[d=16dh+8b+j][q=q32]
        h8 qf[2];
        #pragma unroll
        for (int dh = 0; dh < 2; ++dh)
            qf[dh] = *(const h8*)(qb + (rowbase + q0 + q32) * 128 + h * 32 + 16 * dh + 8 * b);

        f32x16 O;
        #pragma unroll
        for (int i = 0; i < 16; ++i) O[i] = 0.f;
        float m = -1e30f, l = 0.f;

        #pragma unroll
        for (int ch = 0; ch < 2; ++ch) {
            // scores for 4 key-tiles of 32: lane holds S[key=32ktt+(r&3)+8(r>>2)+4b][q]
            f32x16 acc[4];
            #pragma unroll
            for (int kq = 0; kq < 4; ++kq) {
                const int ktt = ch * 4 + kq;
                #pragma unroll
                for (int rq = 0; rq < 4; ++rq) {
                    f32x4 b1v = *(const f32x4*)(b1row + 32 * ktt + 8 * rq + 4 * b);
                    f32x4 b2v = *(const f32x4*)(b2 + 32 * ktt + 8 * rq + 4 * b);
                    #pragma unroll
                    for (int i = 0; i < 4; ++i) acc[kq][4 * rq + i] = b1v[i] + b2v[i];
                }
                #pragma unroll
                for (int dh = 0; dh < 2; ++dh) {
                    h8 kf = *(const h8*)(klds + (ktt * 4 + dh * 2 + b) * 512 + q32 * 16);
                    acc[kq] = __builtin_amdgcn_mfma_f32_32x32x16_f16(kf, qf[dh], acc[kq], 0, 0, 0);
                }
            }

            // chunk softmax (row q=q32): in-lane over 64 + exchange with lane^32
            float cmx = acc[0][0];
            #pragma unroll
            for (int kq = 0; kq < 4; ++kq)
                #pragma unroll
                for (int i = 0; i < 16; ++i) cmx = fmaxf(cmx, acc[kq][i]);
            cmx = fmaxf(cmx, __shfl_xor(cmx, 32));
            const float mn = fmaxf(m, cmx);
            const float scale = __expf(m - mn);
            float cs = 0.f;
            #pragma unroll
            for (int kq = 0; kq < 4; ++kq)
                #pragma unroll
                for (int i = 0; i < 16; ++i) {
                    float p = __expf(acc[kq][i] - mn);
                    acc[kq][i] = p;
                    cs += p;
                }
            cs += __shfl_xor(cs, 32);
            l = l * scale + cs;
            m = mn;
            #pragma unroll
            for (int i = 0; i < 16; ++i) O[i] *= scale;

            // PV over this chunk's 8 key-tiles of 16
            #pragma unroll
            for (int kt = 0; kt < 8; ++kt) {
                const int e = 8 * (kt & 1);
                const f32x16& a = acc[kt >> 1];
                h4 lowh  = {(f16)a[e + 0], (f16)a[e + 1], (f16)a[e + 2], (f16)a[e + 3]};
                h4 highh = {(f16)a[e + 4], (f16)a[e + 5], (f16)a[e + 6], (f16)a[e + 7]};
                u32x2 low  = __builtin_bit_cast(u32x2, lowh);
                u32x2 high = __builtin_bit_cast(u32x2, highh);
                u32x2 swl, swh;
                swl.x = (u32)__shfl_xor((int)low.x, 32);
                swl.y = (u32)__shfl_xor((int)low.y, 32);
                swh.x = (u32)__shfl_xor((int)high.x, 32);
                swh.y = (u32)__shfl_xor((int)high.y, 32);
                u32x4 wfr;
                wfr.x = b ? swh.x : low.x;
                wfr.y = b ? swh.y : low.y;
                wfr.z = b ? high.x : swl.x;
                wfr.w = b ? high.y : swl.y;
                h8 pfrag = __builtin_bit_cast(h8, wfr);
                h8 vf = *(const h8*)(vlds + ((ch * 8 + kt) * 2 + b) * 512 + q32 * 16);
                O = __builtin_amdgcn_mfma_f32_32x32x16_f16(vf, pfrag, O, 0, 0, 0);
            }
        }

        // epilogue: lane holds O[q=q32][d=(r&3)+8(r>>2)+4b]; normalize, gate, h4 store
        const float inv_l = 1.f / l;
        #pragma unroll
        for (int rq = 0; rq < 4; ++rq) {
            size_t idx = (rowbase + q0 + q32) * 128 + h * 32 + 8 * rq + 4 * b;
            h4 g4 = *(const h4*)(gb + idx);
            h4 o4;
            #pragma unroll
            for (int i = 0; i < 4; ++i)
                o4[i] = (f16)(O[4 * rq + i] * inv_l * (float)g4[i]);
            *(h4*)(ob + idx) = o4;
        }
    }
}

// ---------------- Kernel C: output GEMM (f16 MFMA, fp32 out + bo) ----------------
__global__ __launch_bounds__(256) void out_mfma(
    const f16* __restrict__ ob, const float* __restrict__ wo,
    const float* __restrict__ bo, float* __restrict__ out)
{
    __shared__ char lds[65536];
    char* xl = lds;
    char* wl = lds + 32768;
    const int t = threadIdx.x;
    const int lane = t & 63, wave = t >> 6;
    const int wr = wave >> 1, wc = wave & 1;
    const int lo = lane & 15, hi = lane >> 4;
    const int row0 = blockIdx.x * 128;

    // stage ob tile (already f16): 16B chunks, swizzled
    #pragma unroll
    for (int j = 0; j < 8; ++j) {
        int f = t + 256 * j;
        int row = f >> 4, c8 = f & 15;
        h8 v = *(const h8*)(ob + (size_t)(row0 + row) * 128 + c8 * 8);
        *(h8*)(xl + row * 256 + ((c8 ^ (row & 7)) << 4)) = v;
    }
    // stage wo fp32 -> f16
    #pragma unroll
    for (int j = 0; j < 16; ++j) {
        int f = t + 256 * j;
        int row = f >> 5, c4 = f & 31;
        float4 v = *(const float4*)(wo + (size_t)row * 128 + c4 * 4);
        h4 hv = {(f16)v.x, (f16)v.y, (f16)v.z, (f16)v.w};
        *(h4*)(wl + row * 256 + (((c4 >> 1) ^ (row & 7)) << 4) + ((c4 & 1) << 3)) = hv;
    }
    __syncthreads();

    f32x4 acc[4][4];
    #pragma unroll
    for (int m = 0; m < 4; ++m)
        #pragma unroll
        for (int n = 0; n < 4; ++n) acc[m][n] = (f32x4){0.f, 0.f, 0.f, 0.f};

    #pragma unroll
    for (int kk = 0; kk < 4; ++kk) {
        const int swz = ((hi + 4 * kk) ^ (lo & 7)) << 4;
        h8 af[4], bf[4];
        #pragma unroll
        for (int m = 0; m < 4; ++m)
            af[m] = *(const h8*)(xl + (lo + 16 * m + 64 * wr) * 256 + swz);
        #pragma unroll
        for (int n = 0; n < 4; ++n)
            bf[n] = *(const h8*)(wl + (lo + 16 * n + 64 * wc) * 256 + swz);
        #pragma unroll
        for (int m = 0; m < 4; ++m)
            #pragma unroll
            for (int n = 0; n < 4; ++n)
                acc[m][n] = __builtin_amdgcn_mfma_f32_16x16x32_f16(af[m], bf[n], acc[m][n], 0, 0, 0);
    }

    #pragma unroll
    for (int n = 0; n < 4; ++n) {
        const int col = 64 * wc + 16 * n + lo;
        const float bov = bo[col];
        #pragma unroll
        for (int m = 0; m < 4; ++m)
            #pragma unroll
            for (int r = 0; r < 4; ++r)
                out[(size_t)(row0 + 64 * wr + 16 * m + 4 * hi + r) * 128 + col] = acc[m][n][r] + bov;
    }
}

extern "C" void kernel_launch(void* const* d_in, const int* in_sizes, int n_in,
                              void* d_out, int out_size, void* d_ws, size_t ws_size,
                              hipStream_t stream)
{
    const float* q_x   = (const float*)d_in[0];
    const float* kv_x  = (const float*)d_in[1];
    const float* bias1 = (const float*)d_in[2];
    const float* bias2 = (const float*)d_in[3];
    const float* wq    = (const float*)d_in[4];
    const float* wk    = (const float*)d_in[5];
    const float* wv    = (const float*)d_in[6];
    const float* wg    = (const float*)d_in[7];
    const float* bg    = (const float*)d_in[8];
    const float* wo    = (const float*)d_in[9];
    const float* bo    = (const float*)d_in[10];
    float* out = (float*)d_out;

    const size_t RC = (size_t)65536 * 128;
    f16* ws  = (f16*)d_ws;
    f16* qb  = ws;
    f16* kb  = ws + RC;
    f16* vbT = ws + 2 * RC;
    f16* gb  = ws + 3 * RC;
    f16* ob  = ws + 4 * RC;

    proj_mfma<<<dim3(512, 2), 256, 0, stream>>>(q_x, kv_x, wq, wk, wv, wg, bg, qb, kb, vbT, gb);
    attn_mfma<<<dim3(256, 4), 256, 0, stream>>>(qb, kb, vbT, gb, bias1, bias2, ob);
    out_mfma<<<512, 256, 0, stream>>>(ob, wo, bo, out);
}

// Round 7
// 216.587 us; speedup vs baseline: 1.9642x; 1.9642x over previous
//
#include <hip/hip_runtime.h>
#include <math.h>

typedef _Float16 f16;
typedef _Float16 h4 __attribute__((ext_vector_type(4)));
typedef _Float16 h8 __attribute__((ext_vector_type(8)));
typedef float f32x4 __attribute__((ext_vector_type(4)));
typedef float f32x16 __attribute__((ext_vector_type(16)));
typedef unsigned int u32;
typedef u32 u32x2 __attribute__((ext_vector_type(2)));
typedef u32 u32x4 __attribute__((ext_vector_type(4)));

#define QSCALE 0.17677669529663689f  // 1/sqrt(32)

// ---------------- Kernel A: projection GEMM (f16 MFMA) ----------------
// grid (512 row-tiles, 2 phases). phase0: q_x -> {q(scaled), g(sigmoid)};
// phase1: kv_x -> {k, v(transposed store)}. Block 256 thr = 4 waves (2x2),
// out tile 128x128 per weight. LDS: X 32KB + W 32KB, XOR-swizzled 16B chunks.
__global__ __launch_bounds__(256) void proj_mfma(
    const float* __restrict__ q_x, const float* __restrict__ kv_x,
    const float* __restrict__ wq, const float* __restrict__ wk,
    const float* __restrict__ wv, const float* __restrict__ wg,
    const float* __restrict__ bg,
    f16* __restrict__ qb, f16* __restrict__ kb,
    f16* __restrict__ vbT, f16* __restrict__ gb)
{
    __shared__ char lds[65536];
    char* xl = lds;
    char* wl = lds + 32768;
    const int t = threadIdx.x;
    const int lane = t & 63, wave = t >> 6;
    const int wr = wave >> 1, wc = wave & 1;
    const int lo = lane & 15, hi = lane >> 4;
    const int phase = blockIdx.y;
    const int row0 = blockIdx.x * 128;
    const float* xsrc = phase ? kv_x : q_x;

    // stage X tile 128x128 fp32 -> f16 swizzled LDS
    #pragma unroll
    for (int j = 0; j < 16; ++j) {
        int f = t + 256 * j;
        int row = f >> 5, c4 = f & 31;
        float4 v = *(const float4*)(xsrc + (size_t)(row0 + row) * 128 + c4 * 4);
        h4 hv = {(f16)v.x, (f16)v.y, (f16)v.z, (f16)v.w};
        *(h4*)(xl + row * 256 + (((c4 >> 1) ^ (row & 7)) << 4) + ((c4 & 1) << 3)) = hv;
    }

    for (int sub = 0; sub < 2; ++sub) {
        const int pid = phase * 2 + sub;
        const float* w = (pid == 0) ? wq : (pid == 1) ? wg : (pid == 2) ? wk : wv;
        __syncthreads();  // xl ready (sub0) / wl reads done (sub1)
        #pragma unroll
        for (int j = 0; j < 16; ++j) {
            int f = t + 256 * j;
            int row = f >> 5, c4 = f & 31;
            float4 v = *(const float4*)(w + (size_t)row * 128 + c4 * 4);
            h4 hv = {(f16)v.x, (f16)v.y, (f16)v.z, (f16)v.w};
            *(h4*)(wl + row * 256 + (((c4 >> 1) ^ (row & 7)) << 4) + ((c4 & 1) << 3)) = hv;
        }
        __syncthreads();

        f32x4 acc[4][4];
        #pragma unroll
        for (int m = 0; m < 4; ++m)
            #pragma unroll
            for (int n = 0; n < 4; ++n) acc[m][n] = (f32x4){0.f, 0.f, 0.f, 0.f};

        #pragma unroll
        for (int kk = 0; kk < 4; ++kk) {
            const int swz = ((hi + 4 * kk) ^ (lo & 7)) << 4;
            h8 af[4], bf[4];
            #pragma unroll
            for (int m = 0; m < 4; ++m)
                af[m] = *(const h8*)(xl + (lo + 16 * m + 64 * wr) * 256 + swz);
            #pragma unroll
            for (int n = 0; n < 4; ++n)
                bf[n] = *(const h8*)(wl + (lo + 16 * n + 64 * wc) * 256 + swz);
            #pragma unroll
            for (int m = 0; m < 4; ++m)
                #pragma unroll
                for (int n = 0; n < 4; ++n)
                    acc[m][n] = __builtin_amdgcn_mfma_f32_16x16x32_f16(af[m], bf[n], acc[m][n], 0, 0, 0);
        }

        // epilogue: D[row=(l>>4)*4+r][col=l&15]
        #pragma unroll
        for (int n = 0; n < 4; ++n) {
            const int col = 64 * wc + 16 * n + lo;
            const float bgv = (pid == 1) ? bg[col] : 0.f;
            #pragma unroll
            for (int m = 0; m < 4; ++m) {
                if (pid == 3) {
                    // V transposed: vbT[((s*4+h)*32+dh)*256 + key]
                    int rg = row0 + 64 * wr + 16 * m + 4 * hi;
                    int sidx = rg >> 8, key = rg & 255;
                    int hh = col >> 5, dh = col & 31;
                    h4 hv = {(f16)acc[m][n][0], (f16)acc[m][n][1],
                             (f16)acc[m][n][2], (f16)acc[m][n][3]};
                    *(h4*)(vbT + (((size_t)sidx * 4 + hh) * 32 + dh) * 256 + key) = hv;
                } else {
                    f16* dst = (pid == 0) ? qb : (pid == 1) ? gb : kb;
                    #pragma unroll
                    for (int r = 0; r < 4; ++r) {
                        int rg = row0 + 64 * wr + 16 * m + 4 * hi + r;
                        float v = acc[m][n][r];
                        if (pid == 0) v *= QSCALE;
                        else if (pid == 1) v = 1.f / (1.f + __expf(-(v + bgv)));
                        dst[(size_t)rg * 128 + col] = (f16)v;
                    }
                }
            }
        }
    }
}

// ---------------- Kernel B: attention (swapped 32x32x16, chunked online softmax) ----------------
// grid (s=256, h=4); 4 waves; wave does 2 strips of 32 q (2 passes).
// K,V staged ONCE per block into LDS fragment-slot layout (linear 16B/lane reads).
// Keys processed in 2 chunks of 128 (acc[4] = 64 VGPR, fits 128-reg budget with
// no spill) with one online-softmax merge. QK^T as mfma(K,Q) -> D[key][q=lane&31];
// bias1 C-init float4-vectorized; softmax in-lane + shfl_xor(32).
// NOTE: launch_bounds MUST stay (256,2): (256,4) clamps VGPR to 64 -> 625MB spill (round 6).
__global__ __launch_bounds__(256, 2) void attn_mfma(
    const f16* __restrict__ qb, const f16* __restrict__ kb,
    const f16* __restrict__ vbT, const f16* __restrict__ gb,
    const float* __restrict__ bias1, const float* __restrict__ bias2,
    f16* __restrict__ ob)
{
    __shared__ char kvlds[32768];
    char* klds = kvlds;
    char* vlds = kvlds + 16384;
    const int s = blockIdx.x, h = blockIdx.y;
    const int t = threadIdx.x, wave = t >> 6, lane = t & 63;
    const int q32 = lane & 31;   // q column (QK, PV outputs); d row for V A-frag
    const int b = lane >> 5;     // lane half
    const size_t rowbase = (size_t)s * 256;
    const f16* kslab = kb + rowbase * 128 + h * 32;           // K[key][d], row 128
    const f16* vslab = vbT + ((size_t)s * 4 + h) * 32 * 256;  // V^T[d][key]
    const float* b1 = bias1 + (size_t)h * 65536;              // [q][k]
    const float* b2 = bias2 + (size_t)s * 256;                // [k]

    // ---- stage K: chunks (key, c): d-halves 8c..8c+7; slot = (key>>5)*4 + c ----
    #pragma unroll
    for (int it = 0; it < 4; ++it) {
        int idx = t + 256 * it;
        int key = idx >> 2, c = idx & 3;
        h8 v = *(const h8*)(kslab + (size_t)key * 128 + c * 8);
        *(h8*)(klds + ((key >> 5) * 4 + c) * 512 + (key & 31) * 16) = v;
    }
    // ---- stage V: chunks (d, kc): keys 8kc..8kc+7; slot = kc ----
    #pragma unroll
    for (int it = 0; it < 4; ++it) {
        int idx = t + 256 * it;
        int d = idx & 31, kc = idx >> 5;
        h8 v = *(const h8*)(vslab + (size_t)d * 256 + kc * 8);
        *(h8*)(vlds + kc * 512 + d * 16) = v;
    }
    __syncthreads();

    for (int pass = 0; pass < 2; ++pass) {
        const int q0 = pass * 128 + wave * 32;
        const float* b1row = b1 + (size_t)(q0 + q32) * 256;

        // Q B-frags: B[d=16dh+8b+j][q=q32]
        h8 qf[2];
        #pragma unroll
        for (int dh = 0; dh < 2; ++dh)
            qf[dh] = *(const h8*)(qb + (rowbase + q0 + q32) * 128 + h * 32 + 16 * dh + 8 * b);

        f32x16 O;
        #pragma unroll
        for (int i = 0; i < 16; ++i) O[i] = 0.f;
        float m = -1e30f, l = 0.f;

        #pragma unroll
        for (int ch = 0; ch < 2; ++ch) {
            // scores for 4 key-tiles of 32: lane holds S[key=32ktt+(r&3)+8(r>>2)+4b][q]
            f32x16 acc[4];
            #pragma unroll
            for (int kq = 0; kq < 4; ++kq) {
                const int ktt = ch * 4 + kq;
                #pragma unroll
                for (int rq = 0; rq < 4; ++rq) {
                    f32x4 b1v = *(const f32x4*)(b1row + 32 * ktt + 8 * rq + 4 * b);
                    f32x4 b2v = *(const f32x4*)(b2 + 32 * ktt + 8 * rq + 4 * b);
                    #pragma unroll
                    for (int i = 0; i < 4; ++i) acc[kq][4 * rq + i] = b1v[i] + b2v[i];
                }
                #pragma unroll
                for (int dh = 0; dh < 2; ++dh) {
                    h8 kf = *(const h8*)(klds + (ktt * 4 + dh * 2 + b) * 512 + q32 * 16);
                    acc[kq] = __builtin_amdgcn_mfma_f32_32x32x16_f16(kf, qf[dh], acc[kq], 0, 0, 0);
                }
            }

            // chunk softmax (row q=q32): in-lane over 64 + exchange with lane^32
            float cmx = acc[0][0];
            #pragma unroll
            for (int kq = 0; kq < 4; ++kq)
                #pragma unroll
                for (int i = 0; i < 16; ++i) cmx = fmaxf(cmx, acc[kq][i]);
            cmx = fmaxf(cmx, __shfl_xor(cmx, 32));
            const float mn = fmaxf(m, cmx);
            const float scale = __expf(m - mn);
            float cs = 0.f;
            #pragma unroll
            for (int kq = 0; kq < 4; ++kq)
                #pragma unroll
                for (int i = 0; i < 16; ++i) {
                    float p = __expf(acc[kq][i] - mn);
                    acc[kq][i] = p;
                    cs += p;
                }
            cs += __shfl_xor(cs, 32);
            l = l * scale + cs;
            m = mn;
            #pragma unroll
            for (int i = 0; i < 16; ++i) O[i] *= scale;

            // PV over this chunk's 8 key-tiles of 16
            #pragma unroll
            for (int kt = 0; kt < 8; ++kt) {
                const int e = 8 * (kt & 1);
                const f32x16& a = acc[kt >> 1];
                h4 lowh  = {(f16)a[e + 0], (f16)a[e + 1], (f16)a[e + 2], (f16)a[e + 3]};
                h4 highh = {(f16)a[e + 4], (f16)a[e + 5], (f16)a[e + 6], (f16)a[e + 7]};
                u32x2 low  = __builtin_bit_cast(u32x2, lowh);
                u32x2 high = __builtin_bit_cast(u32x2, highh);
                u32x2 swl, swh;
                swl.x = (u32)__shfl_xor((int)low.x, 32);
                swl.y = (u32)__shfl_xor((int)low.y, 32);
                swh.x = (u32)__shfl_xor((int)high.x, 32);
                swh.y = (u32)__shfl_xor((int)high.y, 32);
                u32x4 wfr;
                wfr.x = b ? swh.x : low.x;
                wfr.y = b ? swh.y : low.y;
                wfr.z = b ? high.x : swl.x;
                wfr.w = b ? high.y : swl.y;
                h8 pfrag = __builtin_bit_cast(h8, wfr);
                h8 vf = *(const h8*)(vlds + ((ch * 8 + kt) * 2 + b) * 512 + q32 * 16);
                O = __builtin_amdgcn_mfma_f32_32x32x16_f16(vf, pfrag, O, 0, 0, 0);
            }
        }

        // epilogue: lane holds O[q=q32][d=(r&3)+8(r>>2)+4b]; normalize, gate, h4 store
        const float inv_l = 1.f / l;
        #pragma unroll
        for (int rq = 0; rq < 4; ++rq) {
            size_t idx = (rowbase + q0 + q32) * 128 + h * 32 + 8 * rq + 4 * b;
            h4 g4 = *(const h4*)(gb + idx);
            h4 o4;
            #pragma unroll
            for (int i = 0; i < 4; ++i)
                o4[i] = (f16)(O[4 * rq + i] * inv_l * (float)g4[i]);
            *(h4*)(ob + idx) = o4;
        }
    }
}

// ---------------- Kernel C: output GEMM (f16 MFMA, fp32 out + bo) ----------------
__global__ __launch_bounds__(256) void out_mfma(
    const f16* __restrict__ ob, const float* __restrict__ wo,
    const float* __restrict__ bo, float* __restrict__ out)
{
    __shared__ char lds[65536];
    char* xl = lds;
    char* wl = lds + 32768;
    const int t = threadIdx.x;
    const int lane = t & 63, wave = t >> 6;
    const int wr = wave >> 1, wc = wave & 1;
    const int lo = lane & 15, hi = lane >> 4;
    const int row0 = blockIdx.x * 128;

    // stage ob tile (already f16): 16B chunks, swizzled
    #pragma unroll
    for (int j = 0; j < 8; ++j) {
        int f = t + 256 * j;
        int row = f >> 4, c8 = f & 15;
        h8 v = *(const h8*)(ob + (size_t)(row0 + row) * 128 + c8 * 8);
        *(h8*)(xl + row * 256 + ((c8 ^ (row & 7)) << 4)) = v;
    }
    // stage wo fp32 -> f16
    #pragma unroll
    for (int j = 0; j < 16; ++j) {
        int f = t + 256 * j;
        int row = f >> 5, c4 = f & 31;
        float4 v = *(const float4*)(wo + (size_t)row * 128 + c4 * 4);
        h4 hv = {(f16)v.x, (f16)v.y, (f16)v.z, (f16)v.w};
        *(h4*)(wl + row * 256 + (((c4 >> 1) ^ (row & 7)) << 4) + ((c4 & 1) << 3)) = hv;
    }
    __syncthreads();

    f32x4 acc[4][4];
    #pragma unroll
    for (int m = 0; m < 4; ++m)
        #pragma unroll
        for (int n = 0; n < 4; ++n) acc[m][n] = (f32x4){0.f, 0.f, 0.f, 0.f};

    #pragma unroll
    for (int kk = 0; kk < 4; ++kk) {
        const int swz = ((hi + 4 * kk) ^ (lo & 7)) << 4;
        h8 af[4], bf[4];
        #pragma unroll
        for (int m = 0; m < 4; ++m)
            af[m] = *(const h8*)(xl + (lo + 16 * m + 64 * wr) * 256 + swz);
        #pragma unroll
        for (int n = 0; n < 4; ++n)
            bf[n] = *(const h8*)(wl + (lo + 16 * n + 64 * wc) * 256 + swz);
        #pragma unroll
        for (int m = 0; m < 4; ++m)
            #pragma unroll
            for (int n = 0; n < 4; ++n)
                acc[m][n] = __builtin_amdgcn_mfma_f32_16x16x32_f16(af[m], bf[n], acc[m][n], 0, 0, 0);
    }

    #pragma unroll
    for (int n = 0; n < 4; ++n) {
        const int col = 64 * wc + 16 * n + lo;
        const float bov = bo[col];
        #pragma unroll
        for (int m = 0; m < 4; ++m)
            #pragma unroll
            for (int r = 0; r < 4; ++r)
                out[(size_t)(row0 + 64 * wr + 16 * m + 4 * hi + r) * 128 + col] = acc[m][n][r] + bov;
    }
}

extern "C" void kernel_launch(void* const* d_in, const int* in_sizes, int n_in,
                              void* d_out, int out_size, void* d_ws, size_t ws_size,
                              hipStream_t stream)
{
    const float* q_x   = (const float*)d_in[0];
    const float* kv_x  = (const float*)d_in[1];
    const float* bias1 = (const float*)d_in[2];
    const float* bias2 = (const float*)d_in[3];
    const float* wq    = (const float*)d_in[4];
    const float* wk    = (const float*)d_in[5];
    const float* wv    = (const float*)d_in[6];
    const float* wg    = (const float*)d_in[7];
    const float* bg    = (const float*)d_in[8];
    const float* wo    = (const float*)d_in[9];
    const float* bo    = (const float*)d_in[10];
    float* out = (float*)d_out;

    const size_t RC = (size_t)65536 * 128;
    f16* ws  = (f16*)d_ws;
    f16* qb  = ws;
    f16* kb  = ws + RC;
    f16* vbT = ws + 2 * RC;
    f16* gb  = ws + 3 * RC;
    f16* ob  = ws + 4 * RC;

    proj_mfma<<<dim3(512, 2), 256, 0, stream>>>(q_x, kv_x, wq, wk, wv, wg, bg, qb, kb, vbT, gb);
    attn_mfma<<<dim3(256, 4), 256, 0, stream>>>(qb, kb, vbT, gb, bias1, bias2, ob);
    out_mfma<<<512, 256, 0, stream>>>(ob, wo, bo, out);
}

// Round 8
// 139.732 us; speedup vs baseline: 3.0446x; 1.5500x over previous
//
#include <hip/hip_runtime.h>
#include <math.h>

typedef _Float16 f16;
typedef _Float16 h4 __attribute__((ext_vector_type(4)));
typedef _Float16 h8 __attribute__((ext_vector_type(8)));
typedef float f32x4 __attribute__((ext_vector_type(4)));

#define QSCALE 0.17677669529663689f  // 1/sqrt(32)

// ---------------- Kernel A: projection GEMM (f16 MFMA) ----------------
__global__ __launch_bounds__(256) void proj_mfma(
    const float* __restrict__ q_x, const float* __restrict__ kv_x,
    const float* __restrict__ wq, const float* __restrict__ wk,
    const float* __restrict__ wv, const float* __restrict__ wg,
    const float* __restrict__ bg,
    f16* __restrict__ qb, f16* __restrict__ kb,
    f16* __restrict__ vbT, f16* __restrict__ gb)
{
    __shared__ char lds[65536];
    char* xl = lds;
    char* wl = lds + 32768;
    const int t = threadIdx.x;
    const int lane = t & 63, wave = t >> 6;
    const int wr = wave >> 1, wc = wave & 1;
    const int lo = lane & 15, hi = lane >> 4;
    const int phase = blockIdx.y;
    const int row0 = blockIdx.x * 128;
    const float* xsrc = phase ? kv_x : q_x;

    #pragma unroll
    for (int j = 0; j < 16; ++j) {
        int f = t + 256 * j;
        int row = f >> 5, c4 = f & 31;
        float4 v = *(const float4*)(xsrc + (size_t)(row0 + row) * 128 + c4 * 4);
        h4 hv = {(f16)v.x, (f16)v.y, (f16)v.z, (f16)v.w};
        *(h4*)(xl + row * 256 + (((c4 >> 1) ^ (row & 7)) << 4) + ((c4 & 1) << 3)) = hv;
    }

    for (int sub = 0; sub < 2; ++sub) {
        const int pid = phase * 2 + sub;
        const float* w = (pid == 0) ? wq : (pid == 1) ? wg : (pid == 2) ? wk : wv;
        __syncthreads();
        #pragma unroll
        for (int j = 0; j < 16; ++j) {
            int f = t + 256 * j;
            int row = f >> 5, c4 = f & 31;
            float4 v = *(const float4*)(w + (size_t)row * 128 + c4 * 4);
            h4 hv = {(f16)v.x, (f16)v.y, (f16)v.z, (f16)v.w};
            *(h4*)(wl + row * 256 + (((c4 >> 1) ^ (row & 7)) << 4) + ((c4 & 1) << 3)) = hv;
        }
        __syncthreads();

        f32x4 acc[4][4];
        #pragma unroll
        for (int m = 0; m < 4; ++m)
            #pragma unroll
            for (int n = 0; n < 4; ++n) acc[m][n] = (f32x4){0.f, 0.f, 0.f, 0.f};

        #pragma unroll
        for (int kk = 0; kk < 4; ++kk) {
            const int swz = ((hi + 4 * kk) ^ (lo & 7)) << 4;
            h8 af[4], bf[4];
            #pragma unroll
            for (int m = 0; m < 4; ++m)
                af[m] = *(const h8*)(xl + (lo + 16 * m + 64 * wr) * 256 + swz);
            #pragma unroll
            for (int n = 0; n < 4; ++n)
                bf[n] = *(const h8*)(wl + (lo + 16 * n + 64 * wc) * 256 + swz);
            #pragma unroll
            for (int m = 0; m < 4; ++m)
                #pragma unroll
                for (int n = 0; n < 4; ++n)
                    acc[m][n] = __builtin_amdgcn_mfma_f32_16x16x32_f16(af[m], bf[n], acc[m][n], 0, 0, 0);
        }

        #pragma unroll
        for (int n = 0; n < 4; ++n) {
            const int col = 64 * wc + 16 * n + lo;
            const float bgv = (pid == 1) ? bg[col] : 0.f;
            #pragma unroll
            for (int m = 0; m < 4; ++m) {
                if (pid == 3) {
                    int rg = row0 + 64 * wr + 16 * m + 4 * hi;
                    int sidx = rg >> 8, key = rg & 255;
                    int hh = col >> 5, dh = col & 31;
                    h4 hv = {(f16)acc[m][n][0], (f16)acc[m][n][1],
                             (f16)acc[m][n][2], (f16)acc[m][n][3]};
                    *(h4*)(vbT + (((size_t)sidx * 4 + hh) * 32 + dh) * 256 + key) = hv;
                } else {
                    f16* dst = (pid == 0) ? qb : (pid == 1) ? gb : kb;
                    #pragma unroll
                    for (int r = 0; r < 4; ++r) {
                        int rg = row0 + 64 * wr + 16 * m + 4 * hi + r;
                        float v = acc[m][n][r];
                        if (pid == 0) v *= QSCALE;
                        else if (pid == 1) v = 1.f / (1.f + __expf(-(v + bgv)));
                        dst[(size_t)rg * 128 + col] = (f16)v;
                    }
                }
            }
        }
    }
}

// ---------------- Kernel B: attention (16x16x32 only, chunked online softmax) ----------------
// grid (s=256, h=4); block 256 = 4 waves; wave owns 32 q per pass, 2 passes.
// K,V staged once into LDS fragment-slot layout (conflict-free 16B/lane reads).
// Keys in 2 chunks of 128: acc[2][8] f32x4 = 64 VGPR (f32x4 granularity -> no
// spill; f32x16 variants spilled in rounds 4-7). Non-swapped D[q][key] layout
// (refcheck-proven in rounds 2/3). P routed through per-wave LDS with
// cs = kidx ^ ((row>>2)<<1) swizzle (conflict-free writes, <=4-way reads).
__global__ __launch_bounds__(256, 2) void attn_mfma(
    const f16* __restrict__ qb, const f16* __restrict__ kb,
    const f16* __restrict__ vbT, const f16* __restrict__ gb,
    const float* __restrict__ bias1, const float* __restrict__ bias2,
    f16* __restrict__ ob)
{
    extern __shared__ char smem[];
    char* klds = smem;             // 16 KB: slot((key>>5)*4+c) x [key&31][16B]
    char* vlds = smem + 16384;     // 16 KB: slot(key>>3) x [d][16B]
    char* plds = smem + 32768;     // 32 KB: 4 waves x (32 rows x 256 B)
    const int s = blockIdx.x, h = blockIdx.y;
    const int t = threadIdx.x, wave = t >> 6, lane = t & 63;
    const int lo = lane & 15, hi = lane >> 4;
    char* pw = plds + wave * 8192;
    const size_t rowbase = (size_t)s * 256;
    const f16* kslab = kb + rowbase * 128 + h * 32;           // K[key][d]
    const f16* vslab = vbT + ((size_t)s * 4 + h) * 32 * 256;  // V^T[d][key]
    const float* b1 = bias1 + (size_t)h * 65536;              // [q][k]
    const float* b2 = bias2 + (size_t)s * 256;                // [k]

    // stage K: chunk (key, c): d-octet c; slot = (key>>5)*4 + c
    #pragma unroll
    for (int it = 0; it < 4; ++it) {
        int idx = t + 256 * it;
        int key = idx >> 2, c = idx & 3;
        h8 v = *(const h8*)(kslab + (size_t)key * 128 + c * 8);
        *(h8*)(klds + ((key >> 5) * 4 + c) * 512 + (key & 31) * 16) = v;
    }
    // stage V: chunk (d, kc): key-octet kc; slot = kc
    #pragma unroll
    for (int it = 0; it < 4; ++it) {
        int idx = t + 256 * it;
        int d = idx & 31, kc = idx >> 5;
        h8 v = *(const h8*)(vslab + (size_t)d * 256 + kc * 8);
        *(h8*)(vlds + kc * 512 + d * 16) = v;
    }
    __syncthreads();

    for (int pass = 0; pass < 2; ++pass) {
        const int q0 = pass * 128 + wave * 32;

        // Q A-frags: A[q=16m+lo][d=8hi+j]
        h8 qf[2];
        #pragma unroll
        for (int m = 0; m < 2; ++m)
            qf[m] = *(const h8*)(qb + (rowbase + q0 + 16 * m + lo) * 128 + h * 32 + 8 * hi);

        f32x4 O[2][2];
        float mrun[2][4], lrun[2][4];
        #pragma unroll
        for (int m = 0; m < 2; ++m) {
            #pragma unroll
            for (int n2 = 0; n2 < 2; ++n2) O[m][n2] = (f32x4){0.f, 0.f, 0.f, 0.f};
            #pragma unroll
            for (int r = 0; r < 4; ++r) { mrun[m][r] = -1e30f; lrun[m][r] = 0.f; }
        }

        #pragma unroll
        for (int ch = 0; ch < 2; ++ch) {
            // ---- scores: C-init (bias1+bias2) + QK^T, D[q=16m+4hi+r][key=16nt+lo] ----
            f32x4 acc[2][8];
            #pragma unroll
            for (int m = 0; m < 2; ++m)
                #pragma unroll
                for (int nt = 0; nt < 8; ++nt) {
                    const float b2v = b2[ch * 128 + 16 * nt + lo];
                    #pragma unroll
                    for (int r = 0; r < 4; ++r)
                        acc[m][nt][r] = b1[(size_t)(q0 + 16 * m + 4 * hi + r) * 256
                                           + ch * 128 + 16 * nt + lo] + b2v;
                }
            #pragma unroll
            for (int nt = 0; nt < 8; ++nt) {
                const int ntg = ch * 8 + nt;
                h8 kf = *(const h8*)(klds + ((ntg >> 1) * 4 + hi) * 512
                                     + ((ntg & 1) * 16 + lo) * 16);
                #pragma unroll
                for (int m = 0; m < 2; ++m)
                    acc[m][nt] = __builtin_amdgcn_mfma_f32_16x16x32_f16(qf[m], kf, acc[m][nt], 0, 0, 0);
            }

            // ---- online softmax per row (m,r): in-lane over 8 + 4x shfl_xor(16) ----
            float scale[2][4];
            #pragma unroll
            for (int m = 0; m < 2; ++m)
                #pragma unroll
                for (int r = 0; r < 4; ++r) {
                    float mx = acc[m][0][r];
                    #pragma unroll
                    for (int nt = 1; nt < 8; ++nt) mx = fmaxf(mx, acc[m][nt][r]);
                    #pragma unroll
                    for (int w = 1; w < 16; w <<= 1) mx = fmaxf(mx, __shfl_xor(mx, w, 16));
                    const float mn = fmaxf(mrun[m][r], mx);
                    scale[m][r] = __expf(mrun[m][r] - mn);
                    mrun[m][r] = mn;
                    float sm = 0.f;
                    #pragma unroll
                    for (int nt = 0; nt < 8; ++nt) {
                        float p = __expf(acc[m][nt][r] - mn);
                        acc[m][nt][r] = p;
                        sm += p;
                    }
                    #pragma unroll
                    for (int w = 1; w < 16; w <<= 1) sm += __shfl_xor(sm, w, 16);
                    lrun[m][r] = lrun[m][r] * scale[m][r] + sm;
                }
            #pragma unroll
            for (int m = 0; m < 2; ++m)
                #pragma unroll
                for (int n2 = 0; n2 < 2; ++n2)
                    #pragma unroll
                    for (int r = 0; r < 4; ++r) O[m][n2][r] *= scale[m][r];

            // ---- P -> LDS: cs = kidx ^ ((row>>2)<<1); conflict-free f16 writes ----
            #pragma unroll
            for (int m = 0; m < 2; ++m)
                #pragma unroll
                for (int nt = 0; nt < 8; ++nt)
                    #pragma unroll
                    for (int r = 0; r < 4; ++r) {
                        const int row = 16 * m + 4 * hi + r;
                        const int cs = ((2 * nt + (lo >> 3)) ^ ((4 * m + hi) << 1)) & 15;
                        *(f16*)(pw + row * 256 + cs * 16 + (lo & 7) * 2) = (f16)acc[m][nt][r];
                    }

            // ---- PV: A=P[q=16m+lo][k=32kt+8hi+j] (swizzled b128), B=V from vlds ----
            #pragma unroll
            for (int kt = 0; kt < 4; ++kt) {
                #pragma unroll
                for (int m = 0; m < 2; ++m) {
                    const int row = 16 * m + lo;
                    const int cs = ((4 * kt + hi) ^ ((4 * m + (lo >> 2)) << 1)) & 15;
                    h8 pa = *(const h8*)(pw + row * 256 + cs * 16);
                    #pragma unroll
                    for (int n2 = 0; n2 < 2; ++n2) {
                        h8 vf = *(const h8*)(vlds + (ch * 16 + 4 * kt + hi) * 512
                                             + (16 * n2 + lo) * 16);
                        O[m][n2] = __builtin_amdgcn_mfma_f32_16x16x32_f16(pa, vf, O[m][n2], 0, 0, 0);
                    }
                }
            }
        }

        // ---- epilogue: normalize, gate, store. D[q=16m+4hi+r][d=16n2+lo] ----
        #pragma unroll
        for (int m = 0; m < 2; ++m)
            #pragma unroll
            for (int r = 0; r < 4; ++r) {
                const float inv = 1.f / lrun[m][r];
                #pragma unroll
                for (int n2 = 0; n2 < 2; ++n2) {
                    size_t idx = (rowbase + q0 + 16 * m + 4 * hi + r) * 128
                                 + h * 32 + 16 * n2 + lo;
                    ob[idx] = (f16)(O[m][n2][r] * inv * (float)gb[idx]);
                }
            }
    }
}

// ---------------- Kernel C: output GEMM (f16 MFMA, fp32 out + bo) ----------------
__global__ __launch_bounds__(256) void out_mfma(
    const f16* __restrict__ ob, const float* __restrict__ wo,
    const float* __restrict__ bo, float* __restrict__ out)
{
    __shared__ char lds[65536];
    char* xl = lds;
    char* wl = lds + 32768;
    const int t = threadIdx.x;
    const int lane = t & 63, wave = t >> 6;
    const int wr = wave >> 1, wc = wave & 1;
    const int lo = lane & 15, hi = lane >> 4;
    const int row0 = blockIdx.x * 128;

    #pragma unroll
    for (int j = 0; j < 8; ++j) {
        int f = t + 256 * j;
        int row = f >> 4, c8 = f & 15;
        h8 v = *(const h8*)(ob + (size_t)(row0 + row) * 128 + c8 * 8);
        *(h8*)(xl + row * 256 + ((c8 ^ (row & 7)) << 4)) = v;
    }
    #pragma unroll
    for (int j = 0; j < 16; ++j) {
        int f = t + 256 * j;
        int row = f >> 5, c4 = f & 31;
        float4 v = *(const float4*)(wo + (size_t)row * 128 + c4 * 4);
        h4 hv = {(f16)v.x, (f16)v.y, (f16)v.z, (f16)v.w};
        *(h4*)(wl + row * 256 + (((c4 >> 1) ^ (row & 7)) << 4) + ((c4 & 1) << 3)) = hv;
    }
    __syncthreads();

    f32x4 acc[4][4];
    #pragma unroll
    for (int m = 0; m < 4; ++m)
        #pragma unroll
        for (int n = 0; n < 4; ++n) acc[m][n] = (f32x4){0.f, 0.f, 0.f, 0.f};

    #pragma unroll
    for (int kk = 0; kk < 4; ++kk) {
        const int swz = ((hi + 4 * kk) ^ (lo & 7)) << 4;
        h8 af[4], bf[4];
        #pragma unroll
        for (int m = 0; m < 4; ++m)
            af[m] = *(const h8*)(xl + (lo + 16 * m + 64 * wr) * 256 + swz);
        #pragma unroll
        for (int n = 0; n < 4; ++n)
            bf[n] = *(const h8*)(wl + (lo + 16 * n + 64 * wc) * 256 + swz);
        #pragma unroll
        for (int m = 0; m < 4; ++m)
            #pragma unroll
            for (int n = 0; n < 4; ++n)
                acc[m][n] = __builtin_amdgcn_mfma_f32_16x16x32_f16(af[m], bf[n], acc[m][n], 0, 0, 0);
    }

    #pragma unroll
    for (int n = 0; n < 4; ++n) {
        const int col = 64 * wc + 16 * n + lo;
        const float bov = bo[col];
        #pragma unroll
        for (int m = 0; m < 4; ++m)
            #pragma unroll
            for (int r = 0; r < 4; ++r)
                out[(size_t)(row0 + 64 * wr + 16 * m + 4 * hi + r) * 128 + col] = acc[m][n][r] + bov;
    }
}

extern "C" void kernel_launch(void* const* d_in, const int* in_sizes, int n_in,
                              void* d_out, int out_size, void* d_ws, size_t ws_size,
                              hipStream_t stream)
{
    const float* q_x   = (const float*)d_in[0];
    const float* kv_x  = (const float*)d_in[1];
    const float* bias1 = (const float*)d_in[2];
    const float* bias2 = (const float*)d_in[3];
    const float* wq    = (const float*)d_in[4];
    const float* wk    = (const float*)d_in[5];
    const float* wv    = (const float*)d_in[6];
    const float* wg    = (const float*)d_in[7];
    const float* bg    = (const float*)d_in[8];
    const float* wo    = (const float*)d_in[9];
    const float* bo    = (const float*)d_in[10];
    float* out = (float*)d_out;

    const size_t RC = (size_t)65536 * 128;
    f16* ws  = (f16*)d_ws;
    f16* qb  = ws;
    f16* kb  = ws + RC;
    f16* vbT = ws + 2 * RC;
    f16* gb  = ws + 3 * RC;
    f16* ob  = ws + 4 * RC;

    proj_mfma<<<dim3(512, 2), 256, 0, stream>>>(q_x, kv_x, wq, wk, wv, wg, bg, qb, kb, vbT, gb);
    attn_mfma<<<dim3(256, 4), 256, 65536, stream>>>(qb, kb, vbT, gb, bias1, bias2, ob);
    out_mfma<<<512, 256, 0, stream>>>(ob, wo, bo, out);
}